// Round 1
// baseline (75.326 us; speedup 1.0000x reference)
//
#include <hip/hip_runtime.h>

// Problem constants (from reference setup_inputs):
//   pred:      [64, 4]   fp32   (d_in[0], 256 elems)
//   fragments: [32, 64, 2] fp32 (d_in[1], 4096 elems) -> 2048 points
//   boundary:  [1, 400, 2] fp32 (d_in[2], 800 elems)
//   out: scalar fp32
#define NBOX 64
#define BP   400
#define NPTS 2048
#define FP   64

// One block per fragment point. 256 threads = 4 waves.
// lane (t&63) owns box (t&63); wave (t>>6) covers a 100-elem chunk of BP.
// Early exit: if the point is inside ANY box, min_b(dist_b * outside_b) == 0.
__global__ __launch_bounds__(256) void coverage_point_kernel(
    const float* __restrict__ pred,      // [64*4]
    const float* __restrict__ frags,     // [2048*2]
    const float* __restrict__ boundary,  // [400*2]
    float* __restrict__ ws)              // [2048] per-point min value
{
    const int t  = threadIdx.x;
    const int pt = blockIdx.x;

    const float px = frags[2 * pt + 0];
    const float py = frags[2 * pt + 1];

    const int b = t & 63;   // box index (same set in every wave)
    const int j = t >> 6;   // wave id = BP chunk id

    // Box params in registers (tiny, L1/L2 resident).
    const float lox = pred[4 * b + 0];
    const float loy = pred[4 * b + 1];
    const float hix = pred[4 * b + 2];
    const float hiy = pred[4 * b + 3];
    const float whx = hix - lox;
    const float why = hiy - loy;

    // inside box b iff lo <= p <= hi (both coords)
    const bool inside = (px >= lox) && (py >= loy) && (hix >= px) && (hiy >= py);

    // Every wave holds the identical 64-box set, so each wave's ballot is the
    // same -> branch is block-uniform; safe w.r.t. __syncthreads below.
    const unsigned long long m = __ballot(inside);
    if (m != 0ULL) {
        if (t == 0) ws[pt] = 0.0f;   // inside some box -> contribution 0
        return;
    }

    // Stage boundary points into LDS (reads below are wave-uniform broadcasts).
    __shared__ float s_bnd[BP * 2];
    __shared__ float s_red[256];
    for (int i = t; i < BP * 2; i += 256) s_bnd[i] = boundary[i];
    __syncthreads();

    // min over this wave's 100 boundary samples for box b
    float mind = 1e30f;
    const int k0 = j * (BP / 4);
    #pragma unroll 4
    for (int k = 0; k < BP / 4; ++k) {
        const int bp = k0 + k;
        const float bx  = s_bnd[2 * bp + 0];
        const float by  = s_bnd[2 * bp + 1];
        const float bpx = bx * whx + lox;   // box boundary sample point
        const float bpy = by * why + loy;
        const float dx  = px - bpx;
        const float dy  = py - bpy;
        const float d   = dx * dx + dy * dy;
        mind = fminf(mind, d);
    }

    // Reduce the 4 per-wave partial mins for each box (via LDS),
    // then min across the 64 boxes (point is outside ALL boxes here,
    // so every box's outside factor is 1).
    s_red[t] = mind;
    __syncthreads();
    if (t < 64) {
        float v = fminf(fminf(s_red[t], s_red[t + 64]),
                        fminf(s_red[t + 128], s_red[t + 192]));
        #pragma unroll
        for (int off = 32; off; off >>= 1)
            v = fminf(v, __shfl_down(v, off));
        if (t == 0) ws[pt] = v;
    }
}

// Single-block tree reduction of the 2048 per-point values; scale by 1/FP.
__global__ __launch_bounds__(256) void coverage_reduce_kernel(
    const float* __restrict__ ws, float* __restrict__ out)
{
    __shared__ float s[4];
    const int t = threadIdx.x;
    float acc = 0.0f;
    #pragma unroll
    for (int i = 0; i < NPTS / 256; ++i)
        acc += ws[t + i * 256];
    #pragma unroll
    for (int off = 32; off; off >>= 1)
        acc += __shfl_down(acc, off);
    if ((t & 63) == 0) s[t >> 6] = acc;
    __syncthreads();
    if (t == 0)
        out[0] = (s[0] + s[1] + s[2] + s[3]) * (1.0f / (float)FP);
}

extern "C" void kernel_launch(void* const* d_in, const int* in_sizes, int n_in,
                              void* d_out, int out_size, void* d_ws, size_t ws_size,
                              hipStream_t stream) {
    const float* pred     = (const float*)d_in[0];
    const float* frags    = (const float*)d_in[1];
    const float* boundary = (const float*)d_in[2];
    float* ws  = (float*)d_ws;   // 2048 floats (8 KB) — ws re-poisoned each call,
                                 // but kernel 1 writes every slot before kernel 2 reads.
    float* out = (float*)d_out;

    coverage_point_kernel<<<NPTS, 256, 0, stream>>>(pred, frags, boundary, ws);
    coverage_reduce_kernel<<<1, 256, 0, stream>>>(ws, out);
}

// Round 2
// 72.548 us; speedup vs baseline: 1.0383x; 1.0383x over previous
//
#include <hip/hip_runtime.h>

// Problem constants (from reference setup_inputs):
//   pred:      [64, 4]     fp32  (d_in[0])
//   fragments: [32, 64, 2] fp32  (d_in[1]) -> 2048 points
//   boundary:  [1, 400, 2] fp32  (d_in[2])
//   out: scalar fp32 = sum_pts min_b( sqdist(pt, box_b boundary) * outside_b ) / 64
#define NBOX 64
#define BP   400
#define NPTS 2048
#define FP   64

// One block per fragment point, 256 thr = 4 waves.
// lane (t&63) owns box (t&63) (same mapping in every wave, so the inside-test
// ballot is block-uniform); wave (t>>6) covers a 100-sample chunk of BP.
// If the point is inside ANY box, min_b(dist_b * outside_b) == 0 -> early exit.
// Otherwise all outside factors are 1 -> plain min over (box, BP), one
// atomicAdd(out, min/FP) per contributing block (~17% of 2048 blocks).
__global__ __launch_bounds__(256) void coverage_kernel(
    const float* __restrict__ pred,      // [64*4]
    const float* __restrict__ frags,     // [2048*2]
    const float* __restrict__ boundary,  // [400*2]
    float* __restrict__ out)             // [1], zeroed by memset node
{
    const int t  = threadIdx.x;
    const int pt = blockIdx.x;
    const int b  = t & 63;   // box index
    const int j  = t >> 6;   // wave id = BP chunk

    const float px = frags[2 * pt + 0];
    const float py = frags[2 * pt + 1];

    const float lox = pred[4 * b + 0];
    const float loy = pred[4 * b + 1];
    const float hix = pred[4 * b + 2];
    const float hiy = pred[4 * b + 3];

    const bool inside = (px >= lox) && (py >= loy) && (hix >= px) && (hiy >= py);
    // Identical ballot in all 4 waves -> block-uniform branch (safe vs barrier).
    if (__ballot(inside) != 0ULL) return;   // contribution exactly 0

    // Stage boundary into LDS: 800 floats = 200 float4, one vec-load per thread.
    __shared__ float4 s_bnd4[BP / 2];        // 200 float4 = 400 (x,y) pairs
    __shared__ float  s_red[256];
    if (t < BP / 2) s_bnd4[t] = ((const float4*)boundary)[t];
    __syncthreads();

    const float whx = hix - lox;
    const float why = hiy - loy;
    const float ax  = px - lox;              // dx = ax - bx*whx
    const float ay  = py - loy;

    const float2* s_bnd = (const float2*)s_bnd4;
    float mind = 1e30f;
    const int k0 = j * (BP / 4);
    #pragma unroll 5
    for (int k = 0; k < BP / 4; ++k) {
        const float2 bxy = s_bnd[k0 + k];    // wave-uniform addr -> broadcast
        const float dx = fmaf(-whx, bxy.x, ax);
        const float dy = fmaf(-why, bxy.y, ay);
        const float d  = fmaf(dy, dy, dx * dx);
        mind = fminf(mind, d);
    }

    // Min across the 4 waves per box (LDS), then across 64 boxes (shuffle).
    s_red[t] = mind;
    __syncthreads();
    if (t < 64) {
        float v = fminf(fminf(s_red[t], s_red[t + 64]),
                        fminf(s_red[t + 128], s_red[t + 192]));
        #pragma unroll
        for (int off = 32; off; off >>= 1)
            v = fminf(v, __shfl_down(v, off));
        if (t == 0)
            atomicAdd(out, v * (1.0f / (float)FP));
    }
}

extern "C" void kernel_launch(void* const* d_in, const int* in_sizes, int n_in,
                              void* d_out, int out_size, void* d_ws, size_t ws_size,
                              hipStream_t stream) {
    const float* pred     = (const float*)d_in[0];
    const float* frags    = (const float*)d_in[1];
    const float* boundary = (const float*)d_in[2];
    float* out = (float*)d_out;

    // d_out is re-poisoned to 0xAA before every timed call -> zero it here
    // (graph-legal: becomes a memset node).
    hipMemsetAsync(out, 0, sizeof(float), stream);
    coverage_kernel<<<NPTS, 256, 0, stream>>>(pred, frags, boundary, out);
}